// Round 7
// baseline (221.313 us; speedup 1.0000x reference)
//
#include <hip/hip_runtime.h>

// LocalSelfAttention2d fused MFMA, R7: in-register Q/K/P redistribution via
// ds_bpermute (replaces 5 serial LDS write->read generations of R6). Only VT
// (true transpose) stays in per-wave LDS. 4 barriers, wave = head.
// B=4, CIN=HC=256, heads=8, dh=32, P=8, img 128x128, pad 4/4, 17x17 windows.

typedef __attribute__((ext_vector_type(8))) short bf16x8;
typedef __attribute__((ext_vector_type(4))) float f32x4;

#define NWROW 17
#define NWIN  289
#define ATT_SCALE 0.17677669529663687f  // 1/sqrt(32)

// LDS geometry (ushort units)
#define XS_STRIDE 264                    // 528B rows (16B aligned)
#define XS_SIZE   (64 * XS_STRIDE)       // 16896 ush = 33792 B (os, ys overlay this)
#define WPRIV     2304                   // per-wave VT: 32 rows x stride 72
#define LDS_USH   (XS_SIZE + 8 * WPRIV)  // 35328 ush = 70656 B -> 2 blocks/CU

__device__ __forceinline__ ushort f2bf(float f) {
    unsigned u = __float_as_uint(f);
    u += 0x7FFFu + ((u >> 16) & 1u);   // RNE
    return (ushort)(u >> 16);
}
__device__ __forceinline__ unsigned pack2(float a, float b) {
    return (unsigned)f2bf(a) | ((unsigned)f2bf(b) << 16);
}

// D-layout -> A/B-fragment redistribution (derivation in round notes):
// target lane (g = lane>>4, c = lane&15) elem e needs source tile (g>>1),
// source lane 32*(g&1)+c (e=0..3, regs e) / +16 (e=4..7, regs e-4).
// wa/wb = packed reg-pairs (r0r1, r2r3) of the two candidate source tiles.
__device__ __forceinline__ bf16x8 redist(unsigned wa01, unsigned wa23,
                                         unsigned wb01, unsigned wb23,
                                         int selb, int L0) {
    union { unsigned u[4]; bf16x8 v; } r;
    unsigned x0a = __shfl((int)wa01, L0),      x1a = __shfl((int)wa23, L0);
    unsigned x2a = __shfl((int)wa01, L0 + 16), x3a = __shfl((int)wa23, L0 + 16);
    unsigned x0b = __shfl((int)wb01, L0),      x1b = __shfl((int)wb23, L0);
    unsigned x2b = __shfl((int)wb01, L0 + 16), x3b = __shfl((int)wb23, L0 + 16);
    r.u[0] = selb ? x0b : x0a;  r.u[1] = selb ? x1b : x1a;
    r.u[2] = selb ? x2b : x2a;  r.u[3] = selb ? x3b : x3a;
    return r.v;
}

__global__ void lsa_wconv(const float* __restrict__ wqkv,
                          const float* __restrict__ wout,
                          ushort* __restrict__ dst)
{
    int n = blockIdx.x * 256 + threadIdx.x;   // 1024 x 256 = 262144
    float v = (n < 196608) ? wqkv[n] : wout[n - 196608];
    dst[n] = f2bf(v);
}

__global__ __launch_bounds__(512, 4)
void lsa_fused(const float* __restrict__ x,
               const float* __restrict__ bqkv,
               const float* __restrict__ posb,
               const float* __restrict__ bout,
               const ushort* __restrict__ wqkvb,
               const ushort* __restrict__ woutb,
               float* __restrict__ y)
{
    __shared__ __align__(16) ushort sm[LDS_USH];

    const int t    = threadIdx.x;
    const int wv   = t >> 6;        // wave = head
    const int lane = t & 63;
    const int g    = lane >> 4;     // 0..3
    const int c    = lane & 15;     // 0..15
    const int head = wv;
    const int selb = (lane >> 5) & 1;           // g>>1
    const int L0   = ((lane >> 4) & 1) * 32 + c;

    // bijective XCD chunk swizzle (nwg=1156: q=144, r=4)
    const int orig = blockIdx.x;
    const int xcd  = orig & 7;
    const int idx  = orig >> 3;
    const int bid  = (xcd < 4 ? xcd * 145 : 580 + (xcd - 4) * 144) + idx;

    const int b   = bid / NWIN;
    const int win = bid - b * NWIN;
    const int wi  = win / NWROW;
    const int wj  = win - wi * NWROW;
    const int hbase = wi * 8 - 4;
    const int wbase = wj * 8 - 4;

    // ---------------- phase 0: stage x tile (bf16 [pos][ch]) ----------------
    #pragma unroll
    for (int i = 0; i < 8; ++i) {
        int id = (i << 9) + t;
        int ch = id >> 4;
        int qd = id & 15;           // hh = qd>>1, wquad = qd&1
        int h  = hbase + (qd >> 1);
        int w0 = wbase + (qd & 1) * 4;
        f32x4 v = (f32x4){0.f, 0.f, 0.f, 0.f};
        if ((unsigned)h < 128u && (unsigned)w0 < 125u)
            v = *(const f32x4*)&x[(((size_t)b * 256 + ch) * 128 + h) * 128 + w0];
        ushort bs[4] = {f2bf(v[0]), f2bf(v[1]), f2bf(v[2]), f2bf(v[3])};
        #pragma unroll
        for (int e = 0; e < 4; ++e) {
            int ee = (e + qd) & 3;
            sm[(qd * 4 + ee) * XS_STRIDE + ch] = bs[ee];
        }
    }
    __syncthreads();   // B0

    ushort* priv = &sm[XS_SIZE + wv * WPRIV];   // VT only: [32 d][stride 72]

    // ---------------- pass A: q,k projection (4 m-tiles x 4 p-tiles) ----------------
    f32x4 acc[4][4];
    #pragma unroll
    for (int i = 0; i < 4; ++i)
        #pragma unroll
        for (int j = 0; j < 4; ++j)
            acc[i][j] = (f32x4){0.f, 0.f, 0.f, 0.f};

    const ushort* wr[4];
    #pragma unroll
    for (int j = 0; j < 4; ++j) {
        int m0 = (j >> 1) * 256 + head * 32 + (j & 1) * 16;   // sect 0=q,1=k
        wr[j] = wqkvb + (size_t)(m0 + c) * 256;
    }

    #pragma unroll
    for (int ks = 0; ks < 8; ++ks) {
        bf16x8 bfr[4];
        #pragma unroll
        for (int pt = 0; pt < 4; ++pt)
            bfr[pt] = *(const bf16x8*)&sm[(pt * 16 + c) * XS_STRIDE + ks * 32 + 8 * g];
        #pragma unroll
        for (int j = 0; j < 4; ++j) {
            bf16x8 afr = *(const bf16x8*)(wr[j] + ks * 32 + 8 * g);
            #pragma unroll
            for (int pt = 0; pt < 4; ++pt)
                acc[j][pt] = __builtin_amdgcn_mfma_f32_16x16x32_bf16(afr, bfr[pt], acc[j][pt], 0, 0, 0);
        }
    }

    // q: bias+posbias+scale, pack, redistribute -> qf[qt] (no LDS)
    f32x4 bq0 = *(const f32x4*)&bqkv[head * 32 + 4 * g];
    f32x4 bq1 = *(const f32x4*)&bqkv[head * 32 + 16 + 4 * g];
    f32x4 bk0 = *(const f32x4*)&bqkv[256 + head * 32 + 4 * g];
    f32x4 bk1 = *(const f32x4*)&bqkv[256 + head * 32 + 16 + 4 * g];

    bf16x8 qf[4], kf[4];
    #pragma unroll
    for (int qt = 0; qt < 4; ++qt) {
        const int pos = qt * 16 + c;
        const float* pb0 = posb + (size_t)(head * 32 + 4 * g) * 64 + pos;
        const float* pb1 = pb0 + 16 * 64;
        unsigned a01 = pack2((acc[0][qt][0] + bq0[0] + pb0[0])   * ATT_SCALE,
                             (acc[0][qt][1] + bq0[1] + pb0[64])  * ATT_SCALE);
        unsigned a23 = pack2((acc[0][qt][2] + bq0[2] + pb0[128]) * ATT_SCALE,
                             (acc[0][qt][3] + bq0[3] + pb0[192]) * ATT_SCALE);
        unsigned b01 = pack2((acc[1][qt][0] + bq1[0] + pb1[0])   * ATT_SCALE,
                             (acc[1][qt][1] + bq1[1] + pb1[64])  * ATT_SCALE);
        unsigned b23 = pack2((acc[1][qt][2] + bq1[2] + pb1[128]) * ATT_SCALE,
                             (acc[1][qt][3] + bq1[3] + pb1[192]) * ATT_SCALE);
        qf[qt] = redist(a01, a23, b01, b23, selb, L0);
    }
    #pragma unroll
    for (int kt = 0; kt < 4; ++kt) {
        unsigned a01 = pack2(acc[2][kt][0] + bk0[0], acc[2][kt][1] + bk0[1]);
        unsigned a23 = pack2(acc[2][kt][2] + bk0[2], acc[2][kt][3] + bk0[3]);
        unsigned b01 = pack2(acc[3][kt][0] + bk1[0], acc[3][kt][1] + bk1[1]);
        unsigned b23 = pack2(acc[3][kt][2] + bk1[2], acc[3][kt][3] + bk1[3]);
        kf[kt] = redist(a01, a23, b01, b23, selb, L0);
    }

    // ---------------- pass B: v projection (2 m-tiles x 4 p-tiles) ----------------
    f32x4 av[2][4];
    #pragma unroll
    for (int i = 0; i < 2; ++i)
        #pragma unroll
        for (int j = 0; j < 4; ++j)
            av[i][j] = (f32x4){0.f, 0.f, 0.f, 0.f};
    const ushort* wv0 = wqkvb + (size_t)(512 + head * 32 + c) * 256;
    const ushort* wv1 = wqkvb + (size_t)(512 + head * 32 + 16 + c) * 256;

    #pragma unroll
    for (int ks = 0; ks < 8; ++ks) {
        bf16x8 bfr[4];
        #pragma unroll
        for (int pt = 0; pt < 4; ++pt)
            bfr[pt] = *(const bf16x8*)&sm[(pt * 16 + c) * XS_STRIDE + ks * 32 + 8 * g];
        bf16x8 a0 = *(const bf16x8*)(wv0 + ks * 32 + 8 * g);
        bf16x8 a1 = *(const bf16x8*)(wv1 + ks * 32 + 8 * g);
        #pragma unroll
        for (int pt = 0; pt < 4; ++pt) {
            av[0][pt] = __builtin_amdgcn_mfma_f32_16x16x32_bf16(a0, bfr[pt], av[0][pt], 0, 0, 0);
            av[1][pt] = __builtin_amdgcn_mfma_f32_16x16x32_bf16(a1, bfr[pt], av[1][pt], 0, 0, 0);
        }
    }

    // v epilogue -> VT[32 d][64 pos] stride 72 (the only LDS intermediate)
    f32x4 bv0 = *(const f32x4*)&bqkv[512 + head * 32 + 4 * g];
    f32x4 bv1 = *(const f32x4*)&bqkv[512 + head * 32 + 16 + 4 * g];
    #pragma unroll
    for (int pt = 0; pt < 4; ++pt) {
        #pragma unroll
        for (int r = 0; r < 4; ++r) {
            priv[(4 * g + r) * 72 + pt * 16 + c]        = f2bf(av[0][pt][r] + bv0[r]);
            priv[(16 + 4 * g + r) * 72 + pt * 16 + c]   = f2bf(av[1][pt][r] + bv1[r]);
        }
    }

    // ---------------- attention (wave-private, no barriers) ----------------
    f32x4 s[4][4];   // [kt][qt]: D row = key kt*16+4g+r, col = query qt*16+c
    #pragma unroll
    for (int kt = 0; kt < 4; ++kt)
        #pragma unroll
        for (int qt = 0; qt < 4; ++qt)
            s[kt][qt] = __builtin_amdgcn_mfma_f32_16x16x32_bf16(kf[kt], qf[qt],
                                                                (f32x4){0.f,0.f,0.f,0.f}, 0, 0, 0);

    float rinv[4];
    #pragma unroll
    for (int qt = 0; qt < 4; ++qt) {
        float mx = s[0][qt][0];
        #pragma unroll
        for (int kt = 0; kt < 4; ++kt)
            #pragma unroll
            for (int r = 0; r < 4; ++r)
                mx = fmaxf(mx, s[kt][qt][r]);
        mx = fmaxf(mx, __shfl_xor(mx, 16));
        mx = fmaxf(mx, __shfl_xor(mx, 32));
        float sum = 0.f;
        #pragma unroll
        for (int kt = 0; kt < 4; ++kt)
            #pragma unroll
            for (int r = 0; r < 4; ++r) {
                s[kt][qt][r] = __expf(s[kt][qt][r] - mx);
                sum += s[kt][qt][r];
            }
        sum += __shfl_xor(sum, 16);
        sum += __shfl_xor(sum, 32);
        rinv[qt] = 1.0f / sum;
    }

    // P redistribution in-register: pf[qt][k2] (kt pair 2k2 / 2k2+1 selected by g>>1)
    bf16x8 pf[4][2];
    #pragma unroll
    for (int qt = 0; qt < 4; ++qt) {
        unsigned p01[4], p23[4];
        #pragma unroll
        for (int kt = 0; kt < 4; ++kt) {
            p01[kt] = pack2(s[kt][qt][0], s[kt][qt][1]);
            p23[kt] = pack2(s[kt][qt][2], s[kt][qt][3]);
        }
        pf[qt][0] = redist(p01[0], p23[0], p01[1], p23[1], selb, L0);
        pf[qt][1] = redist(p01[2], p23[2], p01[3], p23[3], selb, L0);
    }

    // vf from VT (same-wave RAW through in-order DS pipe)
    bf16x8 vf[2][2];
    #pragma unroll
    for (int dt = 0; dt < 2; ++dt)
        #pragma unroll
        for (int k2 = 0; k2 < 2; ++k2)
            vf[dt][k2] = *(const bf16x8*)&priv[(dt * 16 + c) * 72 + k2 * 32 + 8 * g];

    f32x4 o[2][4];
    #pragma unroll
    for (int dt = 0; dt < 2; ++dt)
        #pragma unroll
        for (int qt = 0; qt < 4; ++qt)
            o[dt][qt] = (f32x4){0.f,0.f,0.f,0.f};
    #pragma unroll
    for (int k2 = 0; k2 < 2; ++k2)
        #pragma unroll
        for (int dt = 0; dt < 2; ++dt)
            #pragma unroll
            for (int qt = 0; qt < 4; ++qt)
                o[dt][qt] = __builtin_amdgcn_mfma_f32_16x16x32_bf16(vf[dt][k2], pf[qt][k2], o[dt][qt], 0, 0, 0);

    __syncthreads();   // B1: every wave done reading xs; o may overlay it

    // o -> os[pos][ch] (xs overlay)
    #pragma unroll
    for (int dt = 0; dt < 2; ++dt)
        #pragma unroll
        for (int qt = 0; qt < 4; ++qt) {
            const int pos = qt * 16 + c;
            const int ch0 = head * 32 + dt * 16 + 4 * g;
            float rv = rinv[qt];
            *(unsigned*)&sm[pos * XS_STRIDE + ch0]     = pack2(o[dt][qt][0]*rv, o[dt][qt][1]*rv);
            *(unsigned*)&sm[pos * XS_STRIDE + ch0 + 2] = pack2(o[dt][qt][2]*rv, o[dt][qt][3]*rv);
        }
    __syncthreads();   // B2: os complete

    // ---------------- out projection: wave owns out-ch wv*32..+31, K=256 ----------------
    f32x4 ya[2][4];
    #pragma unroll
    for (int i = 0; i < 2; ++i)
        #pragma unroll
        for (int j = 0; j < 4; ++j)
            ya[i][j] = (f32x4){0.f,0.f,0.f,0.f};

    const ushort* wo0 = woutb + (size_t)(wv * 32 + c) * 256;
    const ushort* wo1 = woutb + (size_t)(wv * 32 + 16 + c) * 256;

    #pragma unroll
    for (int ks = 0; ks < 8; ++ks) {
        bf16x8 ofr[4];
        #pragma unroll
        for (int pt = 0; pt < 4; ++pt)
            ofr[pt] = *(const bf16x8*)&sm[(pt * 16 + c) * XS_STRIDE + ks * 32 + 8 * g];
        bf16x8 a0 = *(const bf16x8*)(wo0 + ks * 32 + 8 * g);
        bf16x8 a1 = *(const bf16x8*)(wo1 + ks * 32 + 8 * g);
        #pragma unroll
        for (int pt = 0; pt < 4; ++pt) {
            ya[0][pt] = __builtin_amdgcn_mfma_f32_16x16x32_bf16(a0, ofr[pt], ya[0][pt], 0, 0, 0);
            ya[1][pt] = __builtin_amdgcn_mfma_f32_16x16x32_bf16(a1, ofr[pt], ya[1][pt], 0, 0, 0);
        }
    }
    __syncthreads();   // B3: os reads done; ys may overlay

    // ---------------- epilogue: per-wave LDS transpose -> float4 y stores ----------------
    float* ys = (float*)sm;           // [128 col][66] f32; rows wave-private
    #pragma unroll
    for (int mt = 0; mt < 2; ++mt) {
        f32x4 bo = *(const f32x4*)&bout[wv * 32 + mt * 16 + 4 * g];
        #pragma unroll
        for (int pt = 0; pt < 4; ++pt) {
            const int pos = pt * 16 + c;
            #pragma unroll
            for (int r = 0; r < 4; ++r)
                ys[(wv * 16 + 4 * g + r) * 66 + pos] = ya[mt][pt][r] + bo[r];
        }
        #pragma unroll
        for (int k = 0; k < 2; ++k) {
            const int col = wv * 16 + k * 8 + (lane >> 3);
            const int hh  = lane & 7;
            float2 p0 = *(float2*)&ys[col * 66 + hh * 8];
            float2 p1 = *(float2*)&ys[col * 66 + hh * 8 + 2];
            float2 p2 = *(float2*)&ys[col * 66 + hh * 8 + 4];
            float2 p3 = *(float2*)&ys[col * 66 + hh * 8 + 6];
            const int co  = ((col >> 4) * 2 + mt) * 16 + (col & 15);
            const int him = wi * 8 + hh - 4;
            if ((unsigned)him < 128u) {
                float* yrow = y + (((size_t)b * 256 + co) * 128 + him) * 128;
                if (wj > 0)  { f32x4 v0 = {p0.x, p0.y, p1.x, p1.y}; *(f32x4*)&yrow[wbase]     = v0; }
                if (wj < 16) { f32x4 v1 = {p2.x, p2.y, p3.x, p3.y}; *(f32x4*)&yrow[wbase + 4] = v1; }
            }
        }
    }
}

extern "C" void kernel_launch(void* const* d_in, const int* in_sizes, int n_in,
                              void* d_out, int out_size, void* d_ws, size_t ws_size,
                              hipStream_t stream)
{
    const float* x    = (const float*)d_in[0];
    const float* wqkv = (const float*)d_in[1];
    const float* bqkv = (const float*)d_in[2];
    const float* posb = (const float*)d_in[3];
    const float* wout = (const float*)d_in[4];
    const float* bout = (const float*)d_in[5];
    float* y = (float*)d_out;

    ushort* wqkvb = (ushort*)d_ws;            // 196608 bf16
    ushort* woutb = wqkvb + 196608;           // 65536 bf16

    lsa_wconv<<<dim3(1024), dim3(256), 0, stream>>>(wqkv, wout, wqkvb);
    lsa_fused<<<dim3(4 * NWIN), dim3(512), 0, stream>>>(x, bqkv, posb, bout, wqkvb, woutb, y);
}

// Round 8
// 204.181 us; speedup vs baseline: 1.0839x; 1.0839x over previous
//
#include <hip/hip_runtime.h>

// LocalSelfAttention2d fused MFMA, R8: R6 structure + bank-conflict elimination.
// B=4, CIN=HC=256, heads=8, dh=32, P=8, img 128x128, pad 4/4, 17x17 windows.
//
// Changes vs R6 (which passed at 126us):
//  - XS stride 264->260 with XOR swizzle ((row>>2)&7)<<3 on ush index; frag
//    reads as 2x ds_read_b64 (stride 130 dw == 2 mod 4 -> ~2-way banks).
//  - priv strides: Q/K/P 40->36, VT 72->68 (dw stride == 2 mod 4); frag reads
//    as 2x b64. Writes land ~2-way.
//  - everything else identical: wave = head, 4 barriers, sequential per-wave
//    LDS generations Qt->qf->Kt->kf->VT->S->softmax->vf->P0->pf0->P1->pf1.

typedef __attribute__((ext_vector_type(8))) short bf16x8;
typedef __attribute__((ext_vector_type(4))) float f32x4;

#define NWROW 17
#define NWIN  289
#define ATT_SCALE 0.17677669529663687f  // 1/sqrt(32)

// LDS geometry (ushort units)
#define XS_STRIDE 260                    // 520B rows; 130 dw == 2 mod 4
#define XS_SIZE   (64 * XS_STRIDE)       // 16640 ush = 33280 B (os, ys overlay)
#define QK_STRIDE 36                     // 72B rows (18 dw)
#define VT_STRIDE 68                     // 136B rows (34 dw)
#define WPRIV     2304                   // per-wave: Q/K/P 64x36=2304; VT 32x68=2176 overlays
#define LDS_USH   (XS_SIZE + 8 * WPRIV)  // 35072 ush = 70144 B -> 2 blocks/CU

__device__ __forceinline__ ushort f2bf(float f) {
    unsigned u = __float_as_uint(f);
    u += 0x7FFFu + ((u >> 16) & 1u);   // RNE
    return (ushort)(u >> 16);
}
__device__ __forceinline__ unsigned pack2(float a, float b) {
    return (unsigned)f2bf(a) | ((unsigned)f2bf(b) << 16);
}

union U8 { ushort4 q[2]; bf16x8 v; };

// XS access with XOR swizzle (byte ^= ((row>>2)&7)<<4 -> ush ^= ((row>>2)&7)<<3)
__device__ __forceinline__ int xs_idx(int row, int col) {
    return (row * XS_STRIDE + col) ^ (((row >> 2) & 7) << 3);
}
__device__ __forceinline__ bf16x8 xs_frag(const ushort* sm, int row, int col) {
    U8 u;
    u.q[0] = *(const ushort4*)&sm[xs_idx(row, col)];
    u.q[1] = *(const ushort4*)&sm[xs_idx(row, col + 4)];
    return u.v;
}
// priv access (no swizzle; strides chosen conflict-free)
__device__ __forceinline__ bf16x8 pv_frag(const ushort* p, int row, int stride, int col) {
    U8 u;
    u.q[0] = *(const ushort4*)&p[row * stride + col];
    u.q[1] = *(const ushort4*)&p[row * stride + col + 4];
    return u.v;
}

__global__ void lsa_wconv(const float* __restrict__ wqkv,
                          const float* __restrict__ wout,
                          ushort* __restrict__ dst)
{
    int n = blockIdx.x * 256 + threadIdx.x;   // 1024 x 256 = 262144
    float v = (n < 196608) ? wqkv[n] : wout[n - 196608];
    dst[n] = f2bf(v);
}

__global__ __launch_bounds__(512, 4)
void lsa_fused(const float* __restrict__ x,
               const float* __restrict__ bqkv,
               const float* __restrict__ posb,
               const float* __restrict__ bout,
               const ushort* __restrict__ wqkvb,
               const ushort* __restrict__ woutb,
               float* __restrict__ y)
{
    __shared__ __align__(16) ushort sm[LDS_USH];

    const int t    = threadIdx.x;
    const int wv   = t >> 6;        // wave = head
    const int lane = t & 63;
    const int g    = lane >> 4;     // 0..3
    const int c    = lane & 15;     // 0..15
    const int head = wv;

    // bijective XCD chunk swizzle (nwg=1156: q=144, r=4)
    const int orig = blockIdx.x;
    const int xcd  = orig & 7;
    const int idx  = orig >> 3;
    const int bid  = (xcd < 4 ? xcd * 145 : 580 + (xcd - 4) * 144) + idx;

    const int b   = bid / NWIN;
    const int win = bid - b * NWIN;
    const int wi  = win / NWROW;
    const int wj  = win - wi * NWROW;
    const int hbase = wi * 8 - 4;
    const int wbase = wj * 8 - 4;

    // ---------------- phase 0: stage x tile (bf16 [pos][ch], swizzled) ----------------
    #pragma unroll
    for (int i = 0; i < 8; ++i) {
        int id = (i << 9) + t;
        int ch = id >> 4;
        int qd = id & 15;           // hh = qd>>1, wquad = qd&1
        int h  = hbase + (qd >> 1);
        int w0 = wbase + (qd & 1) * 4;
        f32x4 v = (f32x4){0.f, 0.f, 0.f, 0.f};
        if ((unsigned)h < 128u && (unsigned)w0 < 125u)
            v = *(const f32x4*)&x[(((size_t)b * 256 + ch) * 128 + h) * 128 + w0];
        #pragma unroll
        for (int e = 0; e < 4; ++e)
            sm[xs_idx(qd * 4 + e, ch)] = f2bf(v[e]);
    }
    __syncthreads();   // B0

    ushort* priv = &sm[XS_SIZE + wv * WPRIV];

    // ---------------- pass A: q,k projection (4 m-tiles x 4 p-tiles) ----------------
    f32x4 acc[4][4];
    #pragma unroll
    for (int i = 0; i < 4; ++i)
        #pragma unroll
        for (int j = 0; j < 4; ++j)
            acc[i][j] = (f32x4){0.f, 0.f, 0.f, 0.f};

    const ushort* wr[4];
    #pragma unroll
    for (int j = 0; j < 4; ++j) {
        int m0 = (j >> 1) * 256 + head * 32 + (j & 1) * 16;   // sect 0=q,1=k
        wr[j] = wqkvb + (size_t)(m0 + c) * 256;
    }

    #pragma unroll
    for (int ks = 0; ks < 8; ++ks) {
        bf16x8 bfr[4];
        #pragma unroll
        for (int pt = 0; pt < 4; ++pt)
            bfr[pt] = xs_frag(sm, pt * 16 + c, ks * 32 + 8 * g);
        #pragma unroll
        for (int j = 0; j < 4; ++j) {
            bf16x8 afr = *(const bf16x8*)(wr[j] + ks * 32 + 8 * g);
            #pragma unroll
            for (int pt = 0; pt < 4; ++pt)
                acc[j][pt] = __builtin_amdgcn_mfma_f32_16x16x32_bf16(afr, bfr[pt], acc[j][pt], 0, 0, 0);
        }
    }

    // q epilogue -> Qt[pos][32d] stride 36
    #pragma unroll
    for (int mt = 0; mt < 2; ++mt) {
        f32x4 bq = *(const f32x4*)&bqkv[head * 32 + mt * 16 + 4 * g];
        #pragma unroll
        for (int pt = 0; pt < 4; ++pt) {
            const int pos = pt * 16 + c;
            const float* pb = posb + (size_t)(head * 32 + mt * 16 + 4 * g) * 64 + pos;
            float v0 = (acc[mt][pt][0] + bq[0] + pb[0])   * ATT_SCALE;
            float v1 = (acc[mt][pt][1] + bq[1] + pb[64])  * ATT_SCALE;
            float v2 = (acc[mt][pt][2] + bq[2] + pb[128]) * ATT_SCALE;
            float v3 = (acc[mt][pt][3] + bq[3] + pb[192]) * ATT_SCALE;
            *(unsigned*)&priv[pos * QK_STRIDE + mt * 16 + 4 * g]     = pack2(v0, v1);
            *(unsigned*)&priv[pos * QK_STRIDE + mt * 16 + 4 * g + 2] = pack2(v2, v3);
        }
    }
    bf16x8 qf[4];
    #pragma unroll
    for (int qt = 0; qt < 4; ++qt)
        qf[qt] = pv_frag(priv, qt * 16 + c, QK_STRIDE, 8 * g);

    // k epilogue -> Kt (same slots; same-wave RAW via in-order DS pipe)
    #pragma unroll
    for (int mt = 0; mt < 2; ++mt) {
        f32x4 bk = *(const f32x4*)&bqkv[256 + head * 32 + mt * 16 + 4 * g];
        #pragma unroll
        for (int pt = 0; pt < 4; ++pt) {
            const int pos = pt * 16 + c;
            *(unsigned*)&priv[pos * QK_STRIDE + mt * 16 + 4 * g]     = pack2(acc[mt + 2][pt][0] + bk[0], acc[mt + 2][pt][1] + bk[1]);
            *(unsigned*)&priv[pos * QK_STRIDE + mt * 16 + 4 * g + 2] = pack2(acc[mt + 2][pt][2] + bk[2], acc[mt + 2][pt][3] + bk[3]);
        }
    }
    bf16x8 kf[4];
    #pragma unroll
    for (int kt = 0; kt < 4; ++kt)
        kf[kt] = pv_frag(priv, kt * 16 + c, QK_STRIDE, 8 * g);

    // ---------------- pass B: v projection (2 m-tiles x 4 p-tiles) ----------------
    f32x4 av[2][4];
    #pragma unroll
    for (int i = 0; i < 2; ++i)
        #pragma unroll
        for (int j = 0; j < 4; ++j)
            av[i][j] = (f32x4){0.f, 0.f, 0.f, 0.f};
    const ushort* wv0 = wqkvb + (size_t)(512 + head * 32 + c) * 256;
    const ushort* wv1 = wqkvb + (size_t)(512 + head * 32 + 16 + c) * 256;

    #pragma unroll
    for (int ks = 0; ks < 8; ++ks) {
        bf16x8 bfr[4];
        #pragma unroll
        for (int pt = 0; pt < 4; ++pt)
            bfr[pt] = xs_frag(sm, pt * 16 + c, ks * 32 + 8 * g);
        bf16x8 a0 = *(const bf16x8*)(wv0 + ks * 32 + 8 * g);
        bf16x8 a1 = *(const bf16x8*)(wv1 + ks * 32 + 8 * g);
        #pragma unroll
        for (int pt = 0; pt < 4; ++pt) {
            av[0][pt] = __builtin_amdgcn_mfma_f32_16x16x32_bf16(a0, bfr[pt], av[0][pt], 0, 0, 0);
            av[1][pt] = __builtin_amdgcn_mfma_f32_16x16x32_bf16(a1, bfr[pt], av[1][pt], 0, 0, 0);
        }
    }

    // v epilogue -> VT[32 d][64 pos] stride 68 (overwrites Qt/Kt; qf/kf in regs)
    f32x4 bv0 = *(const f32x4*)&bqkv[512 + head * 32 + 4 * g];
    f32x4 bv1 = *(const f32x4*)&bqkv[512 + head * 32 + 16 + 4 * g];
    #pragma unroll
    for (int pt = 0; pt < 4; ++pt) {
        #pragma unroll
        for (int r = 0; r < 4; ++r) {
            priv[(4 * g + r) * VT_STRIDE + pt * 16 + c]      = f2bf(av[0][pt][r] + bv0[r]);
            priv[(16 + 4 * g + r) * VT_STRIDE + pt * 16 + c] = f2bf(av[1][pt][r] + bv1[r]);
        }
    }

    // ---------------- attention (fully wave-private, no barriers) ----------------
    f32x4 s[4][4];   // [kt][qt]: D row = key kt*16+4g+r, col = query qt*16+c
    #pragma unroll
    for (int kt = 0; kt < 4; ++kt)
        #pragma unroll
        for (int qt = 0; qt < 4; ++qt)
            s[kt][qt] = __builtin_amdgcn_mfma_f32_16x16x32_bf16(kf[kt], qf[qt],
                                                                (f32x4){0.f,0.f,0.f,0.f}, 0, 0, 0);

    float rinv[4];
    #pragma unroll
    for (int qt = 0; qt < 4; ++qt) {
        float mx = s[0][qt][0];
        #pragma unroll
        for (int kt = 0; kt < 4; ++kt)
            #pragma unroll
            for (int r = 0; r < 4; ++r)
                mx = fmaxf(mx, s[kt][qt][r]);
        mx = fmaxf(mx, __shfl_xor(mx, 16));
        mx = fmaxf(mx, __shfl_xor(mx, 32));
        float sum = 0.f;
        #pragma unroll
        for (int kt = 0; kt < 4; ++kt)
            #pragma unroll
            for (int r = 0; r < 4; ++r) {
                s[kt][qt][r] = __expf(s[kt][qt][r] - mx);
                sum += s[kt][qt][r];
            }
        sum += __shfl_xor(sum, 16);
        sum += __shfl_xor(sum, 32);
        rinv[qt] = 1.0f / sum;
    }

    // vf BEFORE P overwrites VT
    bf16x8 vf[2][2];
    #pragma unroll
    for (int dt = 0; dt < 2; ++dt)
        #pragma unroll
        for (int k2 = 0; k2 < 2; ++k2)
            vf[dt][k2] = pv_frag(priv, dt * 16 + c, VT_STRIDE, k2 * 32 + 8 * g);

    // PV in two sequential key-half generations through the same P slots
    f32x4 o[2][4];
    #pragma unroll
    for (int dt = 0; dt < 2; ++dt)
        #pragma unroll
        for (int qt = 0; qt < 4; ++qt)
            o[dt][qt] = (f32x4){0.f,0.f,0.f,0.f};

    #pragma unroll
    for (int k2 = 0; k2 < 2; ++k2) {
        #pragma unroll
        for (int qt = 0; qt < 4; ++qt)
            #pragma unroll
            for (int kl = 0; kl < 2; ++kl) {
                const int kt = k2 * 2 + kl;
                *(unsigned*)&priv[(qt * 16 + c) * QK_STRIDE + kl * 16 + 4 * g]     = pack2(s[kt][qt][0], s[kt][qt][1]);
                *(unsigned*)&priv[(qt * 16 + c) * QK_STRIDE + kl * 16 + 4 * g + 2] = pack2(s[kt][qt][2], s[kt][qt][3]);
            }
        #pragma unroll
        for (int qt = 0; qt < 4; ++qt) {
            bf16x8 pf = pv_frag(priv, qt * 16 + c, QK_STRIDE, 8 * g);
            #pragma unroll
            for (int dt = 0; dt < 2; ++dt)
                o[dt][qt] = __builtin_amdgcn_mfma_f32_16x16x32_bf16(vf[dt][k2], pf, o[dt][qt], 0, 0, 0);
        }
    }

    __syncthreads();   // B1: every wave done reading xs; o may overlay it

    // o -> os[pos][ch] (xs overlay, same swizzle)
    #pragma unroll
    for (int dt = 0; dt < 2; ++dt)
        #pragma unroll
        for (int qt = 0; qt < 4; ++qt) {
            const int pos = qt * 16 + c;
            const int ch0 = head * 32 + dt * 16 + 4 * g;
            float rv = rinv[qt];
            const int i0 = xs_idx(pos, ch0);
            *(unsigned*)&sm[i0]     = pack2(o[dt][qt][0]*rv, o[dt][qt][1]*rv);
            *(unsigned*)&sm[i0 + 2] = pack2(o[dt][qt][2]*rv, o[dt][qt][3]*rv);
        }
    __syncthreads();   // B2: os complete

    // ---------------- out projection: wave owns out-ch wv*32..+31, K=256 ----------------
    f32x4 ya[2][4];
    #pragma unroll
    for (int i = 0; i < 2; ++i)
        #pragma unroll
        for (int j = 0; j < 4; ++j)
            ya[i][j] = (f32x4){0.f,0.f,0.f,0.f};

    const ushort* wo0 = woutb + (size_t)(wv * 32 + c) * 256;
    const ushort* wo1 = woutb + (size_t)(wv * 32 + 16 + c) * 256;

    #pragma unroll
    for (int ks = 0; ks < 8; ++ks) {
        bf16x8 ofr[4];
        #pragma unroll
        for (int pt = 0; pt < 4; ++pt)
            ofr[pt] = xs_frag(sm, pt * 16 + c, ks * 32 + 8 * g);
        bf16x8 a0 = *(const bf16x8*)(wo0 + ks * 32 + 8 * g);
        bf16x8 a1 = *(const bf16x8*)(wo1 + ks * 32 + 8 * g);
        #pragma unroll
        for (int pt = 0; pt < 4; ++pt) {
            ya[0][pt] = __builtin_amdgcn_mfma_f32_16x16x32_bf16(a0, ofr[pt], ya[0][pt], 0, 0, 0);
            ya[1][pt] = __builtin_amdgcn_mfma_f32_16x16x32_bf16(a1, ofr[pt], ya[1][pt], 0, 0, 0);
        }
    }
    __syncthreads();   // B3: os reads done; ys may overlay

    // ---------------- epilogue: per-wave LDS transpose -> float4 y stores ----------------
    float* ys = (float*)sm;           // [128 col][66] f32; rows wave-private
    #pragma unroll
    for (int mt = 0; mt < 2; ++mt) {
        f32x4 bo = *(const f32x4*)&bout[wv * 32 + mt * 16 + 4 * g];
        #pragma unroll
        for (int pt = 0; pt < 4; ++pt) {
            const int pos = pt * 16 + c;
            #pragma unroll
            for (int r = 0; r < 4; ++r)
                ys[(wv * 16 + 4 * g + r) * 66 + pos] = ya[mt][pt][r] + bo[r];
        }
        #pragma unroll
        for (int k = 0; k < 2; ++k) {
            const int col = wv * 16 + k * 8 + (lane >> 3);
            const int hh  = lane & 7;
            float2 p0 = *(float2*)&ys[col * 66 + hh * 8];
            float2 p1 = *(float2*)&ys[col * 66 + hh * 8 + 2];
            float2 p2 = *(float2*)&ys[col * 66 + hh * 8 + 4];
            float2 p3 = *(float2*)&ys[col * 66 + hh * 8 + 6];
            const int co  = ((col >> 4) * 2 + mt) * 16 + (col & 15);
            const int him = wi * 8 + hh - 4;
            if ((unsigned)him < 128u) {
                float* yrow = y + (((size_t)b * 256 + co) * 128 + him) * 128;
                if (wj > 0)  { f32x4 v0 = {p0.x, p0.y, p1.x, p1.y}; *(f32x4*)&yrow[wbase]     = v0; }
                if (wj < 16) { f32x4 v1 = {p2.x, p2.y, p3.x, p3.y}; *(f32x4*)&yrow[wbase + 4] = v1; }
            }
        }
    }
}

extern "C" void kernel_launch(void* const* d_in, const int* in_sizes, int n_in,
                              void* d_out, int out_size, void* d_ws, size_t ws_size,
                              hipStream_t stream)
{
    const float* x    = (const float*)d_in[0];
    const float* wqkv = (const float*)d_in[1];
    const float* bqkv = (const float*)d_in[2];
    const float* posb = (const float*)d_in[3];
    const float* wout = (const float*)d_in[4];
    const float* bout = (const float*)d_in[5];
    float* y = (float*)d_out;

    ushort* wqkvb = (ushort*)d_ws;            // 196608 bf16
    ushort* woutb = wqkvb + 196608;           // 65536 bf16

    lsa_wconv<<<dim3(1024), dim3(256), 0, stream>>>(wqkv, wout, wqkvb);
    lsa_fused<<<dim3(4 * NWIN), dim3(512), 0, stream>>>(x, bqkv, posb, bout, wqkvb, woutb, y);
}

// Round 9
// 143.809 us; speedup vs baseline: 1.5389x; 1.4198x over previous
//
#include <hip/hip_runtime.h>

// LocalSelfAttention2d fused MFMA, R9 = R6 base (126us) + surgical fixes:
//  1) x-staging remap: lane->(chp=t&31, qd=t>>5) => LDS write banks = chp+{4e,16+4e}
//     (32 banks, 2 lanes each = free), packed u32 writes (2 ch/write).
//  2) uint2-paired LDS writes for Qt/Kt/P/os epilogues (half the insts, 2-way).
//  3) s_setprio(1) around MFMA clusters (T5; waves desynced between barriers).
// Everything else identical to R6: wave = head, 4 barriers, sequential per-wave
// private generations Qt->qf->Kt->kf->VT->S->softmax->vf->P0->pf0->P1->pf1.

typedef __attribute__((ext_vector_type(8))) short bf16x8;
typedef __attribute__((ext_vector_type(4))) float f32x4;

#define NWROW 17
#define NWIN  289
#define ATT_SCALE 0.17677669529663687f  // 1/sqrt(32)

// LDS geometry (ushort units) — identical to R6
#define XS_STRIDE 264                    // 528B rows (16B aligned)
#define XS_SIZE   (64 * XS_STRIDE)       // 16896 ush = 33792 B (os, ys overlay)
#define QK_STRIDE 40                     // 80B rows (16B aligned)
#define VT_STRIDE 72                     // 144B rows (16B aligned)
#define WPRIV     2560                   // per-wave private scratch
#define LDS_USH   (XS_SIZE + 8 * WPRIV)  // 37376 ush = 74752 B -> 2 blocks/CU

__device__ __forceinline__ ushort f2bf(float f) {
    unsigned u = __float_as_uint(f);
    u += 0x7FFFu + ((u >> 16) & 1u);   // RNE
    return (ushort)(u >> 16);
}
__device__ __forceinline__ unsigned pack2(float a, float b) {
    return (unsigned)f2bf(a) | ((unsigned)f2bf(b) << 16);
}

__global__ void lsa_wconv(const float* __restrict__ wqkv,
                          const float* __restrict__ wout,
                          ushort* __restrict__ dst)
{
    int n = blockIdx.x * 256 + threadIdx.x;   // 1024 x 256 = 262144
    float v = (n < 196608) ? wqkv[n] : wout[n - 196608];
    dst[n] = f2bf(v);
}

__global__ __launch_bounds__(512, 4)
void lsa_fused(const float* __restrict__ x,
               const float* __restrict__ bqkv,
               const float* __restrict__ posb,
               const float* __restrict__ bout,
               const ushort* __restrict__ wqkvb,
               const ushort* __restrict__ woutb,
               float* __restrict__ y)
{
    __shared__ __align__(16) ushort sm[LDS_USH];

    const int t    = threadIdx.x;
    const int wv   = t >> 6;        // wave = head
    const int lane = t & 63;
    const int g    = lane >> 4;     // 0..3
    const int c    = lane & 15;     // 0..15
    const int head = wv;

    // bijective XCD chunk swizzle (nwg=1156: q=144, r=4)
    const int orig = blockIdx.x;
    const int xcd  = orig & 7;
    const int idx  = orig >> 3;
    const int bid  = (xcd < 4 ? xcd * 145 : 580 + (xcd - 4) * 144) + idx;

    const int b   = bid / NWIN;
    const int win = bid - b * NWIN;
    const int wi  = win / NWROW;
    const int wj  = win - wi * NWROW;
    const int hbase = wi * 8 - 4;
    const int wbase = wj * 8 - 4;

    // ---------------- phase 0: stage x tile (bf16 [pos][ch]) ----------------
    // thread -> (chp, qd): chp = (t&31)+32i (channel pair), qd = t>>5
    // (h = qd>>1, w-half = qd&1). Writes: 4x u32 (ch0,ch0+1 packed), banks
    // chp + {4e,16+4e} -> 32 banks x 2 lanes = conflict-free.
    {
        const int qd = t >> 5;            // 0..15
        const int h  = hbase + (qd >> 1);
        const int w0 = wbase + (qd & 1) * 4;
        const bool inimg = ((unsigned)h < 128u) & ((unsigned)w0 < 125u);
        #pragma unroll
        for (int i = 0; i < 4; ++i) {
            const int chp = (t & 31) + 32 * i;   // 0..127
            const int ch0 = chp * 2;
            f32x4 va = (f32x4){0.f,0.f,0.f,0.f};
            f32x4 vb = (f32x4){0.f,0.f,0.f,0.f};
            if (inimg) {
                const float* px = &x[(((size_t)b * 256 + ch0) * 128 + h) * 128 + w0];
                va = *(const f32x4*)px;
                vb = *(const f32x4*)(px + 16384);
            }
            #pragma unroll
            for (int e = 0; e < 4; ++e)
                *(unsigned*)&sm[(qd * 4 + e) * XS_STRIDE + ch0] = pack2(va[e], vb[e]);
        }
    }
    __syncthreads();   // B0

    ushort* priv = &sm[XS_SIZE + wv * WPRIV];

    // ---------------- pass A: q,k projection (4 m-tiles x 4 p-tiles) ----------------
    f32x4 acc[4][4];
    #pragma unroll
    for (int i = 0; i < 4; ++i)
        #pragma unroll
        for (int j = 0; j < 4; ++j)
            acc[i][j] = (f32x4){0.f, 0.f, 0.f, 0.f};

    const ushort* wr[4];
    #pragma unroll
    for (int j = 0; j < 4; ++j) {
        int m0 = (j >> 1) * 256 + head * 32 + (j & 1) * 16;   // sect 0=q,1=k
        wr[j] = wqkvb + (size_t)(m0 + c) * 256;
    }

    __builtin_amdgcn_s_setprio(1);
    #pragma unroll
    for (int ks = 0; ks < 8; ++ks) {
        bf16x8 bfr[4];
        #pragma unroll
        for (int pt = 0; pt < 4; ++pt)
            bfr[pt] = *(const bf16x8*)&sm[(pt * 16 + c) * XS_STRIDE + ks * 32 + 8 * g];
        #pragma unroll
        for (int j = 0; j < 4; ++j) {
            bf16x8 afr = *(const bf16x8*)(wr[j] + ks * 32 + 8 * g);
            #pragma unroll
            for (int pt = 0; pt < 4; ++pt)
                acc[j][pt] = __builtin_amdgcn_mfma_f32_16x16x32_bf16(afr, bfr[pt], acc[j][pt], 0, 0, 0);
        }
    }
    __builtin_amdgcn_s_setprio(0);

    // q epilogue -> Qt[pos][32d] stride 40 (uint2-paired writes)
    #pragma unroll
    for (int mt = 0; mt < 2; ++mt) {
        f32x4 bq = *(const f32x4*)&bqkv[head * 32 + mt * 16 + 4 * g];
        #pragma unroll
        for (int pt = 0; pt < 4; ++pt) {
            const int pos = pt * 16 + c;
            const float* pb = posb + (size_t)(head * 32 + mt * 16 + 4 * g) * 64 + pos;
            float v0 = (acc[mt][pt][0] + bq[0] + pb[0])   * ATT_SCALE;
            float v1 = (acc[mt][pt][1] + bq[1] + pb[64])  * ATT_SCALE;
            float v2 = (acc[mt][pt][2] + bq[2] + pb[128]) * ATT_SCALE;
            float v3 = (acc[mt][pt][3] + bq[3] + pb[192]) * ATT_SCALE;
            *(uint2*)&priv[pos * QK_STRIDE + mt * 16 + 4 * g] =
                make_uint2(pack2(v0, v1), pack2(v2, v3));
        }
    }
    bf16x8 qf[4];
    #pragma unroll
    for (int qt = 0; qt < 4; ++qt)
        qf[qt] = *(const bf16x8*)&priv[(qt * 16 + c) * QK_STRIDE + 8 * g];

    // k epilogue -> Kt (same slots; same-wave RAW via in-order DS pipe)
    #pragma unroll
    for (int mt = 0; mt < 2; ++mt) {
        f32x4 bk = *(const f32x4*)&bqkv[256 + head * 32 + mt * 16 + 4 * g];
        #pragma unroll
        for (int pt = 0; pt < 4; ++pt) {
            const int pos = pt * 16 + c;
            *(uint2*)&priv[pos * QK_STRIDE + mt * 16 + 4 * g] =
                make_uint2(pack2(acc[mt + 2][pt][0] + bk[0], acc[mt + 2][pt][1] + bk[1]),
                           pack2(acc[mt + 2][pt][2] + bk[2], acc[mt + 2][pt][3] + bk[3]));
        }
    }
    bf16x8 kf[4];
    #pragma unroll
    for (int kt = 0; kt < 4; ++kt)
        kf[kt] = *(const bf16x8*)&priv[(kt * 16 + c) * QK_STRIDE + 8 * g];

    // ---------------- pass B: v projection (2 m-tiles x 4 p-tiles) ----------------
    f32x4 av[2][4];
    #pragma unroll
    for (int i = 0; i < 2; ++i)
        #pragma unroll
        for (int j = 0; j < 4; ++j)
            av[i][j] = (f32x4){0.f, 0.f, 0.f, 0.f};
    const ushort* wv0 = wqkvb + (size_t)(512 + head * 32 + c) * 256;
    const ushort* wv1 = wqkvb + (size_t)(512 + head * 32 + 16 + c) * 256;

    __builtin_amdgcn_s_setprio(1);
    #pragma unroll
    for (int ks = 0; ks < 8; ++ks) {
        bf16x8 bfr[4];
        #pragma unroll
        for (int pt = 0; pt < 4; ++pt)
            bfr[pt] = *(const bf16x8*)&sm[(pt * 16 + c) * XS_STRIDE + ks * 32 + 8 * g];
        bf16x8 a0 = *(const bf16x8*)(wv0 + ks * 32 + 8 * g);
        bf16x8 a1 = *(const bf16x8*)(wv1 + ks * 32 + 8 * g);
        #pragma unroll
        for (int pt = 0; pt < 4; ++pt) {
            av[0][pt] = __builtin_amdgcn_mfma_f32_16x16x32_bf16(a0, bfr[pt], av[0][pt], 0, 0, 0);
            av[1][pt] = __builtin_amdgcn_mfma_f32_16x16x32_bf16(a1, bfr[pt], av[1][pt], 0, 0, 0);
        }
    }
    __builtin_amdgcn_s_setprio(0);

    // v epilogue -> VT[32 d][64 pos] stride 72 (overwrites Qt/Kt; qf/kf in regs)
    f32x4 bv0 = *(const f32x4*)&bqkv[512 + head * 32 + 4 * g];
    f32x4 bv1 = *(const f32x4*)&bqkv[512 + head * 32 + 16 + 4 * g];
    #pragma unroll
    for (int pt = 0; pt < 4; ++pt) {
        #pragma unroll
        for (int r = 0; r < 4; ++r) {
            priv[(4 * g + r) * VT_STRIDE + pt * 16 + c]      = f2bf(av[0][pt][r] + bv0[r]);
            priv[(16 + 4 * g + r) * VT_STRIDE + pt * 16 + c] = f2bf(av[1][pt][r] + bv1[r]);
        }
    }

    // ---------------- attention (fully wave-private, no barriers) ----------------
    f32x4 s[4][4];   // [kt][qt]: D row = key kt*16+4g+r, col = query qt*16+c
    __builtin_amdgcn_s_setprio(1);
    #pragma unroll
    for (int kt = 0; kt < 4; ++kt)
        #pragma unroll
        for (int qt = 0; qt < 4; ++qt)
            s[kt][qt] = __builtin_amdgcn_mfma_f32_16x16x32_bf16(kf[kt], qf[qt],
                                                                (f32x4){0.f,0.f,0.f,0.f}, 0, 0, 0);
    __builtin_amdgcn_s_setprio(0);

    float rinv[4];
    #pragma unroll
    for (int qt = 0; qt < 4; ++qt) {
        float mx = s[0][qt][0];
        #pragma unroll
        for (int kt = 0; kt < 4; ++kt)
            #pragma unroll
            for (int r = 0; r < 4; ++r)
                mx = fmaxf(mx, s[kt][qt][r]);
        mx = fmaxf(mx, __shfl_xor(mx, 16));
        mx = fmaxf(mx, __shfl_xor(mx, 32));
        float sum = 0.f;
        #pragma unroll
        for (int kt = 0; kt < 4; ++kt)
            #pragma unroll
            for (int r = 0; r < 4; ++r) {
                s[kt][qt][r] = __expf(s[kt][qt][r] - mx);
                sum += s[kt][qt][r];
            }
        sum += __shfl_xor(sum, 16);
        sum += __shfl_xor(sum, 32);
        rinv[qt] = 1.0f / sum;
    }

    // vf BEFORE P overwrites VT
    bf16x8 vf[2][2];
    #pragma unroll
    for (int dt = 0; dt < 2; ++dt)
        #pragma unroll
        for (int k2 = 0; k2 < 2; ++k2)
            vf[dt][k2] = *(const bf16x8*)&priv[(dt * 16 + c) * VT_STRIDE + k2 * 32 + 8 * g];

    // PV in two sequential key-half generations through the same P slots
    f32x4 o[2][4];
    #pragma unroll
    for (int dt = 0; dt < 2; ++dt)
        #pragma unroll
        for (int qt = 0; qt < 4; ++qt)
            o[dt][qt] = (f32x4){0.f,0.f,0.f,0.f};

    #pragma unroll
    for (int k2 = 0; k2 < 2; ++k2) {
        #pragma unroll
        for (int qt = 0; qt < 4; ++qt)
            #pragma unroll
            for (int kl = 0; kl < 2; ++kl) {
                const int kt = k2 * 2 + kl;
                *(uint2*)&priv[(qt * 16 + c) * QK_STRIDE + kl * 16 + 4 * g] =
                    make_uint2(pack2(s[kt][qt][0], s[kt][qt][1]),
                               pack2(s[kt][qt][2], s[kt][qt][3]));
            }
        __builtin_amdgcn_s_setprio(1);
        #pragma unroll
        for (int qt = 0; qt < 4; ++qt) {
            bf16x8 pf = *(const bf16x8*)&priv[(qt * 16 + c) * QK_STRIDE + 8 * g];
            #pragma unroll
            for (int dt = 0; dt < 2; ++dt)
                o[dt][qt] = __builtin_amdgcn_mfma_f32_16x16x32_bf16(vf[dt][k2], pf, o[dt][qt], 0, 0, 0);
        }
        __builtin_amdgcn_s_setprio(0);
    }

    __syncthreads();   // B1: every wave done reading xs; o may overlay it

    // o -> os[pos][ch] (xs overlay), uint2-paired
    #pragma unroll
    for (int dt = 0; dt < 2; ++dt)
        #pragma unroll
        for (int qt = 0; qt < 4; ++qt) {
            const int pos = qt * 16 + c;
            const int ch0 = head * 32 + dt * 16 + 4 * g;
            float rv = rinv[qt];
            *(uint2*)&sm[pos * XS_STRIDE + ch0] =
                make_uint2(pack2(o[dt][qt][0]*rv, o[dt][qt][1]*rv),
                           pack2(o[dt][qt][2]*rv, o[dt][qt][3]*rv));
        }
    __syncthreads();   // B2: os complete

    // ---------------- out projection: wave owns out-ch wv*32..+31, K=256 ----------------
    f32x4 ya[2][4];
    #pragma unroll
    for (int i = 0; i < 2; ++i)
        #pragma unroll
        for (int j = 0; j < 4; ++j)
            ya[i][j] = (f32x4){0.f,0.f,0.f,0.f};

    const ushort* wo0 = woutb + (size_t)(wv * 32 + c) * 256;
    const ushort* wo1 = woutb + (size_t)(wv * 32 + 16 + c) * 256;

    __builtin_amdgcn_s_setprio(1);
    #pragma unroll
    for (int ks = 0; ks < 8; ++ks) {
        bf16x8 ofr[4];
        #pragma unroll
        for (int pt = 0; pt < 4; ++pt)
            ofr[pt] = *(const bf16x8*)&sm[(pt * 16 + c) * XS_STRIDE + ks * 32 + 8 * g];
        bf16x8 a0 = *(const bf16x8*)(wo0 + ks * 32 + 8 * g);
        bf16x8 a1 = *(const bf16x8*)(wo1 + ks * 32 + 8 * g);
        #pragma unroll
        for (int pt = 0; pt < 4; ++pt) {
            ya[0][pt] = __builtin_amdgcn_mfma_f32_16x16x32_bf16(a0, ofr[pt], ya[0][pt], 0, 0, 0);
            ya[1][pt] = __builtin_amdgcn_mfma_f32_16x16x32_bf16(a1, ofr[pt], ya[1][pt], 0, 0, 0);
        }
    }
    __builtin_amdgcn_s_setprio(0);
    __syncthreads();   // B3: os reads done; ys may overlay

    // ---------------- epilogue: per-wave LDS transpose -> float4 y stores ----------------
    float* ys = (float*)sm;           // [128 col][66] f32; rows wave-private
    #pragma unroll
    for (int mt = 0; mt < 2; ++mt) {
        f32x4 bo = *(const f32x4*)&bout[wv * 32 + mt * 16 + 4 * g];
        #pragma unroll
        for (int pt = 0; pt < 4; ++pt) {
            const int pos = pt * 16 + c;
            #pragma unroll
            for (int r = 0; r < 4; ++r)
                ys[(wv * 16 + 4 * g + r) * 66 + pos] = ya[mt][pt][r] + bo[r];
        }
        #pragma unroll
        for (int k = 0; k < 2; ++k) {
            const int col = wv * 16 + k * 8 + (lane >> 3);
            const int hh  = lane & 7;
            float2 p0 = *(float2*)&ys[col * 66 + hh * 8];
            float2 p1 = *(float2*)&ys[col * 66 + hh * 8 + 2];
            float2 p2 = *(float2*)&ys[col * 66 + hh * 8 + 4];
            float2 p3 = *(float2*)&ys[col * 66 + hh * 8 + 6];
            const int co  = ((col >> 4) * 2 + mt) * 16 + (col & 15);
            const int him = wi * 8 + hh - 4;
            if ((unsigned)him < 128u) {
                float* yrow = y + (((size_t)b * 256 + co) * 128 + him) * 128;
                if (wj > 0)  { f32x4 v0 = {p0.x, p0.y, p1.x, p1.y}; *(f32x4*)&yrow[wbase]     = v0; }
                if (wj < 16) { f32x4 v1 = {p2.x, p2.y, p3.x, p3.y}; *(f32x4*)&yrow[wbase + 4] = v1; }
            }
        }
    }
}

extern "C" void kernel_launch(void* const* d_in, const int* in_sizes, int n_in,
                              void* d_out, int out_size, void* d_ws, size_t ws_size,
                              hipStream_t stream)
{
    const float* x    = (const float*)d_in[0];
    const float* wqkv = (const float*)d_in[1];
    const float* bqkv = (const float*)d_in[2];
    const float* posb = (const float*)d_in[3];
    const float* wout = (const float*)d_in[4];
    const float* bout = (const float*)d_in[5];
    float* y = (float*)d_out;

    ushort* wqkvb = (ushort*)d_ws;            // 196608 bf16
    ushort* woutb = wqkvb + 196608;           // 65536 bf16

    lsa_wconv<<<dim3(1024), dim3(256), 0, stream>>>(wqkv, wout, wqkvb);
    lsa_fused<<<dim3(4 * NWIN), dim3(512), 0, stream>>>(x, bqkv, posb, bout, wqkvb, woutb, y);
}

// Round 10
// 143.018 us; speedup vs baseline: 1.5474x; 1.0055x over previous
//
#include <hip/hip_runtime.h>

// LocalSelfAttention2d fused MFMA, R10 = R6 base + (uint2 LDS writes, setprio).
// Staging reverted to R6's spill-free form (R9's remap kept 32 regs live -> spill).
// B=4, CIN=HC=256, heads=8, dh=32, P=8, img 128x128, pad 4/4, 17x17 windows.
// Wave = head, 4 barriers, sequential per-wave private LDS generations:
//   Qt->qf->Kt->kf->VT->S->softmax->vf->P0->pf0->P1->pf1.

typedef __attribute__((ext_vector_type(8))) short bf16x8;
typedef __attribute__((ext_vector_type(4))) float f32x4;

#define NWROW 17
#define NWIN  289
#define ATT_SCALE 0.17677669529663687f  // 1/sqrt(32)

// LDS geometry (ushort units) — identical to R6
#define XS_STRIDE 264                    // 528B rows (16B aligned)
#define XS_SIZE   (64 * XS_STRIDE)       // 16896 ush = 33792 B (os, ys overlay)
#define QK_STRIDE 40                     // 80B rows (16B aligned)
#define VT_STRIDE 72                     // 144B rows (16B aligned)
#define WPRIV     2560                   // per-wave private scratch
#define LDS_USH   (XS_SIZE + 8 * WPRIV)  // 37376 ush = 74752 B -> 2 blocks/CU

__device__ __forceinline__ ushort f2bf(float f) {
    unsigned u = __float_as_uint(f);
    u += 0x7FFFu + ((u >> 16) & 1u);   // RNE
    return (ushort)(u >> 16);
}
__device__ __forceinline__ unsigned pack2(float a, float b) {
    return (unsigned)f2bf(a) | ((unsigned)f2bf(b) << 16);
}

__global__ void lsa_wconv(const float* __restrict__ wqkv,
                          const float* __restrict__ wout,
                          ushort* __restrict__ dst)
{
    int n = blockIdx.x * 256 + threadIdx.x;   // 1024 x 256 = 262144
    float v = (n < 196608) ? wqkv[n] : wout[n - 196608];
    dst[n] = f2bf(v);
}

__global__ __launch_bounds__(512, 4)
void lsa_fused(const float* __restrict__ x,
               const float* __restrict__ bqkv,
               const float* __restrict__ posb,
               const float* __restrict__ bout,
               const ushort* __restrict__ wqkvb,
               const ushort* __restrict__ woutb,
               float* __restrict__ y)
{
    __shared__ __align__(16) ushort sm[LDS_USH];

    const int t    = threadIdx.x;
    const int wv   = t >> 6;        // wave = head
    const int lane = t & 63;
    const int g    = lane >> 4;     // 0..3
    const int c    = lane & 15;     // 0..15
    const int head = wv;

    // bijective XCD chunk swizzle (nwg=1156: q=144, r=4)
    const int orig = blockIdx.x;
    const int xcd  = orig & 7;
    const int idx  = orig >> 3;
    const int bid  = (xcd < 4 ? xcd * 145 : 580 + (xcd - 4) * 144) + idx;

    const int b   = bid / NWIN;
    const int win = bid - b * NWIN;
    const int wi  = win / NWROW;
    const int wj  = win - wi * NWROW;
    const int hbase = wi * 8 - 4;
    const int wbase = wj * 8 - 4;

    // ---------------- phase 0: stage x tile (bf16 [pos][ch]) — R6 verbatim ----------------
    #pragma unroll
    for (int i = 0; i < 8; ++i) {
        int id = (i << 9) + t;
        int ch = id >> 4;
        int qd = id & 15;           // hh = qd>>1, wquad = qd&1
        int h  = hbase + (qd >> 1);
        int w0 = wbase + (qd & 1) * 4;
        f32x4 v = (f32x4){0.f, 0.f, 0.f, 0.f};
        if ((unsigned)h < 128u && (unsigned)w0 < 125u)
            v = *(const f32x4*)&x[(((size_t)b * 256 + ch) * 128 + h) * 128 + w0];
        ushort bs[4] = {f2bf(v[0]), f2bf(v[1]), f2bf(v[2]), f2bf(v[3])};
        #pragma unroll
        for (int e = 0; e < 4; ++e) {
            int ee = (e + qd) & 3;
            sm[(qd * 4 + ee) * XS_STRIDE + ch] = bs[ee];
        }
    }
    __syncthreads();   // B0

    ushort* priv = &sm[XS_SIZE + wv * WPRIV];

    // ---------------- pass A: q,k projection (4 m-tiles x 4 p-tiles) ----------------
    f32x4 acc[4][4];
    #pragma unroll
    for (int i = 0; i < 4; ++i)
        #pragma unroll
        for (int j = 0; j < 4; ++j)
            acc[i][j] = (f32x4){0.f, 0.f, 0.f, 0.f};

    const ushort* wr[4];
    #pragma unroll
    for (int j = 0; j < 4; ++j) {
        int m0 = (j >> 1) * 256 + head * 32 + (j & 1) * 16;   // sect 0=q,1=k
        wr[j] = wqkvb + (size_t)(m0 + c) * 256;
    }

    __builtin_amdgcn_s_setprio(1);
    #pragma unroll
    for (int ks = 0; ks < 8; ++ks) {
        bf16x8 bfr[4];
        #pragma unroll
        for (int pt = 0; pt < 4; ++pt)
            bfr[pt] = *(const bf16x8*)&sm[(pt * 16 + c) * XS_STRIDE + ks * 32 + 8 * g];
        #pragma unroll
        for (int j = 0; j < 4; ++j) {
            bf16x8 afr = *(const bf16x8*)(wr[j] + ks * 32 + 8 * g);
            #pragma unroll
            for (int pt = 0; pt < 4; ++pt)
                acc[j][pt] = __builtin_amdgcn_mfma_f32_16x16x32_bf16(afr, bfr[pt], acc[j][pt], 0, 0, 0);
        }
    }
    __builtin_amdgcn_s_setprio(0);

    // q epilogue -> Qt[pos][32d] stride 40 (uint2-paired writes)
    #pragma unroll
    for (int mt = 0; mt < 2; ++mt) {
        f32x4 bq = *(const f32x4*)&bqkv[head * 32 + mt * 16 + 4 * g];
        #pragma unroll
        for (int pt = 0; pt < 4; ++pt) {
            const int pos = pt * 16 + c;
            const float* pb = posb + (size_t)(head * 32 + mt * 16 + 4 * g) * 64 + pos;
            float v0 = (acc[mt][pt][0] + bq[0] + pb[0])   * ATT_SCALE;
            float v1 = (acc[mt][pt][1] + bq[1] + pb[64])  * ATT_SCALE;
            float v2 = (acc[mt][pt][2] + bq[2] + pb[128]) * ATT_SCALE;
            float v3 = (acc[mt][pt][3] + bq[3] + pb[192]) * ATT_SCALE;
            *(uint2*)&priv[pos * QK_STRIDE + mt * 16 + 4 * g] =
                make_uint2(pack2(v0, v1), pack2(v2, v3));
        }
    }
    bf16x8 qf[4];
    #pragma unroll
    for (int qt = 0; qt < 4; ++qt)
        qf[qt] = *(const bf16x8*)&priv[(qt * 16 + c) * QK_STRIDE + 8 * g];

    // k epilogue -> Kt (same slots; same-wave RAW via in-order DS pipe)
    #pragma unroll
    for (int mt = 0; mt < 2; ++mt) {
        f32x4 bk = *(const f32x4*)&bqkv[256 + head * 32 + mt * 16 + 4 * g];
        #pragma unroll
        for (int pt = 0; pt < 4; ++pt) {
            const int pos = pt * 16 + c;
            *(uint2*)&priv[pos * QK_STRIDE + mt * 16 + 4 * g] =
                make_uint2(pack2(acc[mt + 2][pt][0] + bk[0], acc[mt + 2][pt][1] + bk[1]),
                           pack2(acc[mt + 2][pt][2] + bk[2], acc[mt + 2][pt][3] + bk[3]));
        }
    }
    bf16x8 kf[4];
    #pragma unroll
    for (int kt = 0; kt < 4; ++kt)
        kf[kt] = *(const bf16x8*)&priv[(kt * 16 + c) * QK_STRIDE + 8 * g];

    // ---------------- pass B: v projection (2 m-tiles x 4 p-tiles) ----------------
    f32x4 av[2][4];
    #pragma unroll
    for (int i = 0; i < 2; ++i)
        #pragma unroll
        for (int j = 0; j < 4; ++j)
            av[i][j] = (f32x4){0.f, 0.f, 0.f, 0.f};
    const ushort* wv0 = wqkvb + (size_t)(512 + head * 32 + c) * 256;
    const ushort* wv1 = wqkvb + (size_t)(512 + head * 32 + 16 + c) * 256;

    __builtin_amdgcn_s_setprio(1);
    #pragma unroll
    for (int ks = 0; ks < 8; ++ks) {
        bf16x8 bfr[4];
        #pragma unroll
        for (int pt = 0; pt < 4; ++pt)
            bfr[pt] = *(const bf16x8*)&sm[(pt * 16 + c) * XS_STRIDE + ks * 32 + 8 * g];
        bf16x8 a0 = *(const bf16x8*)(wv0 + ks * 32 + 8 * g);
        bf16x8 a1 = *(const bf16x8*)(wv1 + ks * 32 + 8 * g);
        #pragma unroll
        for (int pt = 0; pt < 4; ++pt) {
            av[0][pt] = __builtin_amdgcn_mfma_f32_16x16x32_bf16(a0, bfr[pt], av[0][pt], 0, 0, 0);
            av[1][pt] = __builtin_amdgcn_mfma_f32_16x16x32_bf16(a1, bfr[pt], av[1][pt], 0, 0, 0);
        }
    }
    __builtin_amdgcn_s_setprio(0);

    // v epilogue -> VT[32 d][64 pos] stride 72 (overwrites Qt/Kt; qf/kf in regs)
    f32x4 bv0 = *(const f32x4*)&bqkv[512 + head * 32 + 4 * g];
    f32x4 bv1 = *(const f32x4*)&bqkv[512 + head * 32 + 16 + 4 * g];
    #pragma unroll
    for (int pt = 0; pt < 4; ++pt) {
        #pragma unroll
        for (int r = 0; r < 4; ++r) {
            priv[(4 * g + r) * VT_STRIDE + pt * 16 + c]      = f2bf(av[0][pt][r] + bv0[r]);
            priv[(16 + 4 * g + r) * VT_STRIDE + pt * 16 + c] = f2bf(av[1][pt][r] + bv1[r]);
        }
    }

    // ---------------- attention (fully wave-private, no barriers) ----------------
    f32x4 s[4][4];   // [kt][qt]: D row = key kt*16+4g+r, col = query qt*16+c
    __builtin_amdgcn_s_setprio(1);
    #pragma unroll
    for (int kt = 0; kt < 4; ++kt)
        #pragma unroll
        for (int qt = 0; qt < 4; ++qt)
            s[kt][qt] = __builtin_amdgcn_mfma_f32_16x16x32_bf16(kf[kt], qf[qt],
                                                                (f32x4){0.f,0.f,0.f,0.f}, 0, 0, 0);
    __builtin_amdgcn_s_setprio(0);

    float rinv[4];
    #pragma unroll
    for (int qt = 0; qt < 4; ++qt) {
        float mx = s[0][qt][0];
        #pragma unroll
        for (int kt = 0; kt < 4; ++kt)
            #pragma unroll
            for (int r = 0; r < 4; ++r)
                mx = fmaxf(mx, s[kt][qt][r]);
        mx = fmaxf(mx, __shfl_xor(mx, 16));
        mx = fmaxf(mx, __shfl_xor(mx, 32));
        float sum = 0.f;
        #pragma unroll
        for (int kt = 0; kt < 4; ++kt)
            #pragma unroll
            for (int r = 0; r < 4; ++r) {
                s[kt][qt][r] = __expf(s[kt][qt][r] - mx);
                sum += s[kt][qt][r];
            }
        sum += __shfl_xor(sum, 16);
        sum += __shfl_xor(sum, 32);
        rinv[qt] = 1.0f / sum;
    }

    // vf BEFORE P overwrites VT
    bf16x8 vf[2][2];
    #pragma unroll
    for (int dt = 0; dt < 2; ++dt)
        #pragma unroll
        for (int k2 = 0; k2 < 2; ++k2)
            vf[dt][k2] = *(const bf16x8*)&priv[(dt * 16 + c) * VT_STRIDE + k2 * 32 + 8 * g];

    // PV in two sequential key-half generations through the same P slots
    f32x4 o[2][4];
    #pragma unroll
    for (int dt = 0; dt < 2; ++dt)
        #pragma unroll
        for (int qt = 0; qt < 4; ++qt)
            o[dt][qt] = (f32x4){0.f,0.f,0.f,0.f};

    #pragma unroll
    for (int k2 = 0; k2 < 2; ++k2) {
        #pragma unroll
        for (int qt = 0; qt < 4; ++qt)
            #pragma unroll
            for (int kl = 0; kl < 2; ++kl) {
                const int kt = k2 * 2 + kl;
                *(uint2*)&priv[(qt * 16 + c) * QK_STRIDE + kl * 16 + 4 * g] =
                    make_uint2(pack2(s[kt][qt][0], s[kt][qt][1]),
                               pack2(s[kt][qt][2], s[kt][qt][3]));
            }
        __builtin_amdgcn_s_setprio(1);
        #pragma unroll
        for (int qt = 0; qt < 4; ++qt) {
            bf16x8 pf = *(const bf16x8*)&priv[(qt * 16 + c) * QK_STRIDE + 8 * g];
            #pragma unroll
            for (int dt = 0; dt < 2; ++dt)
                o[dt][qt] = __builtin_amdgcn_mfma_f32_16x16x32_bf16(vf[dt][k2], pf, o[dt][qt], 0, 0, 0);
        }
        __builtin_amdgcn_s_setprio(0);
    }

    __syncthreads();   // B1: every wave done reading xs; o may overlay it

    // o -> os[pos][ch] (xs overlay), uint2-paired
    #pragma unroll
    for (int dt = 0; dt < 2; ++dt)
        #pragma unroll
        for (int qt = 0; qt < 4; ++qt) {
            const int pos = qt * 16 + c;
            const int ch0 = head * 32 + dt * 16 + 4 * g;
            float rv = rinv[qt];
            *(uint2*)&sm[pos * XS_STRIDE + ch0] =
                make_uint2(pack2(o[dt][qt][0]*rv, o[dt][qt][1]*rv),
                           pack2(o[dt][qt][2]*rv, o[dt][qt][3]*rv));
        }
    __syncthreads();   // B2: os complete

    // ---------------- out projection: wave owns out-ch wv*32..+31, K=256 ----------------
    f32x4 ya[2][4];
    #pragma unroll
    for (int i = 0; i < 2; ++i)
        #pragma unroll
        for (int j = 0; j < 4; ++j)
            ya[i][j] = (f32x4){0.f,0.f,0.f,0.f};

    const ushort* wo0 = woutb + (size_t)(wv * 32 + c) * 256;
    const ushort* wo1 = woutb + (size_t)(wv * 32 + 16 + c) * 256;

    __builtin_amdgcn_s_setprio(1);
    #pragma unroll
    for (int ks = 0; ks < 8; ++ks) {
        bf16x8 ofr[4];
        #pragma unroll
        for (int pt = 0; pt < 4; ++pt)
            ofr[pt] = *(const bf16x8*)&sm[(pt * 16 + c) * XS_STRIDE + ks * 32 + 8 * g];
        bf16x8 a0 = *(const bf16x8*)(wo0 + ks * 32 + 8 * g);
        bf16x8 a1 = *(const bf16x8*)(wo1 + ks * 32 + 8 * g);
        #pragma unroll
        for (int pt = 0; pt < 4; ++pt) {
            ya[0][pt] = __builtin_amdgcn_mfma_f32_16x16x32_bf16(a0, ofr[pt], ya[0][pt], 0, 0, 0);
            ya[1][pt] = __builtin_amdgcn_mfma_f32_16x16x32_bf16(a1, ofr[pt], ya[1][pt], 0, 0, 0);
        }
    }
    __builtin_amdgcn_s_setprio(0);
    __syncthreads();   // B3: os reads done; ys may overlay

    // ---------------- epilogue: per-wave LDS transpose -> float4 y stores ----------------
    float* ys = (float*)sm;           // [128 col][66] f32; rows wave-private
    #pragma unroll
    for (int mt = 0; mt < 2; ++mt) {
        f32x4 bo = *(const f32x4*)&bout[wv * 32 + mt * 16 + 4 * g];
        #pragma unroll
        for (int pt = 0; pt < 4; ++pt) {
            const int pos = pt * 16 + c;
            #pragma unroll
            for (int r = 0; r < 4; ++r)
                ys[(wv * 16 + 4 * g + r) * 66 + pos] = ya[mt][pt][r] + bo[r];
        }
        #pragma unroll
        for (int k = 0; k < 2; ++k) {
            const int col = wv * 16 + k * 8 + (lane >> 3);
            const int hh  = lane & 7;
            float2 p0 = *(float2*)&ys[col * 66 + hh * 8];
            float2 p1 = *(float2*)&ys[col * 66 + hh * 8 + 2];
            float2 p2 = *(float2*)&ys[col * 66 + hh * 8 + 4];
            float2 p3 = *(float2*)&ys[col * 66 + hh * 8 + 6];
            const int co  = ((col >> 4) * 2 + mt) * 16 + (col & 15);
            const int him = wi * 8 + hh - 4;
            if ((unsigned)him < 128u) {
                float* yrow = y + (((size_t)b * 256 + co) * 128 + him) * 128;
                if (wj > 0)  { f32x4 v0 = {p0.x, p0.y, p1.x, p1.y}; *(f32x4*)&yrow[wbase]     = v0; }
                if (wj < 16) { f32x4 v1 = {p2.x, p2.y, p3.x, p3.y}; *(f32x4*)&yrow[wbase + 4] = v1; }
            }
        }
    }
}

extern "C" void kernel_launch(void* const* d_in, const int* in_sizes, int n_in,
                              void* d_out, int out_size, void* d_ws, size_t ws_size,
                              hipStream_t stream)
{
    const float* x    = (const float*)d_in[0];
    const float* wqkv = (const float*)d_in[1];
    const float* bqkv = (const float*)d_in[2];
    const float* posb = (const float*)d_in[3];
    const float* wout = (const float*)d_in[4];
    const float* bout = (const float*)d_in[5];
    float* y = (float*)d_out;

    ushort* wqkvb = (ushort*)d_ws;            // 196608 bf16
    ushort* woutb = wqkvb + 196608;           // 65536 bf16

    lsa_wconv<<<dim3(1024), dim3(256), 0, stream>>>(wqkv, wout, wqkvb);
    lsa_fused<<<dim3(4 * NWIN), dim3(512), 0, stream>>>(x, bqkv, posb, bout, wqkvb, woutb, y);
}

// Round 11
// 126.537 us; speedup vs baseline: 1.7490x; 1.1302x over previous
//
#include <hip/hip_runtime.h>

// LocalSelfAttention2d fused MFMA, R11 = exact R6 revert (the 126us anchor).
// B=4, CIN=HC=256, heads=8, dh=32, P=8, img 128x128, pad 4/4, 17x17 win.
//
// Block = (b,win), 512 thr, wave = head. Per-wave 2560-ush private slice reused
// in sequential generations (same-wave RAW via in-order DS pipe, no barriers):
//   Qt[64x32 s40] -> qf -> Kt[64x32 s40] -> kf -> VT[32x64 s72] -> vf
//   -> P0[64x32 s40](keys 0..31) -> pf0 -> P1[same](keys 32..63) -> pf1
// Barriers: B0 x staged; B1 xs dead (os overlays); B2 os ready; B3 os dead (ys).

typedef __attribute__((ext_vector_type(8))) short bf16x8;
typedef __attribute__((ext_vector_type(4))) float f32x4;

#define NWROW 17
#define NWIN  289
#define ATT_SCALE 0.17677669529663687f  // 1/sqrt(32)

// LDS geometry (ushort units)
#define XS_STRIDE 264                    // 528B rows (16B aligned)
#define XS_SIZE   (64 * XS_STRIDE)       // 16896 ush = 33792 B (os, ys overlay this)
#define WPRIV     2560                   // per-wave private scratch
#define LDS_USH   (XS_SIZE + 8 * WPRIV)  // 37376 ush = 74752 B -> 2 blocks/CU

__device__ __forceinline__ ushort f2bf(float f) {
    unsigned u = __float_as_uint(f);
    u += 0x7FFFu + ((u >> 16) & 1u);   // RNE
    return (ushort)(u >> 16);
}
__device__ __forceinline__ unsigned pack2(float a, float b) {
    return (unsigned)f2bf(a) | ((unsigned)f2bf(b) << 16);
}

__global__ void lsa_wconv(const float* __restrict__ wqkv,
                          const float* __restrict__ wout,
                          ushort* __restrict__ dst)
{
    int n = blockIdx.x * 256 + threadIdx.x;   // 1024 x 256 = 262144
    float v = (n < 196608) ? wqkv[n] : wout[n - 196608];
    dst[n] = f2bf(v);
}

__global__ __launch_bounds__(512, 4)
void lsa_fused(const float* __restrict__ x,
               const float* __restrict__ bqkv,
               const float* __restrict__ posb,
               const float* __restrict__ bout,
               const ushort* __restrict__ wqkvb,
               const ushort* __restrict__ woutb,
               float* __restrict__ y)
{
    __shared__ __align__(16) ushort sm[LDS_USH];

    const int t    = threadIdx.x;
    const int wv   = t >> 6;        // wave = head
    const int lane = t & 63;
    const int g    = lane >> 4;     // 0..3
    const int c    = lane & 15;     // 0..15
    const int head = wv;

    // bijective XCD chunk swizzle (nwg=1156: q=144, r=4)
    const int orig = blockIdx.x;
    const int xcd  = orig & 7;
    const int idx  = orig >> 3;
    const int bid  = (xcd < 4 ? xcd * 145 : 580 + (xcd - 4) * 144) + idx;

    const int b   = bid / NWIN;
    const int win = bid - b * NWIN;
    const int wi  = win / NWROW;
    const int wj  = win - wi * NWROW;
    const int hbase = wi * 8 - 4;
    const int wbase = wj * 8 - 4;

    // ---------------- phase 0: stage x tile (bf16 [pos][ch]) ----------------
    #pragma unroll
    for (int i = 0; i < 8; ++i) {
        int id = (i << 9) + t;
        int ch = id >> 4;
        int qd = id & 15;           // hh = qd>>1, wquad = qd&1
        int h  = hbase + (qd >> 1);
        int w0 = wbase + (qd & 1) * 4;
        f32x4 v = (f32x4){0.f, 0.f, 0.f, 0.f};
        if ((unsigned)h < 128u && (unsigned)w0 < 125u)
            v = *(const f32x4*)&x[(((size_t)b * 256 + ch) * 128 + h) * 128 + w0];
        ushort bs[4] = {f2bf(v[0]), f2bf(v[1]), f2bf(v[2]), f2bf(v[3])};
        #pragma unroll
        for (int e = 0; e < 4; ++e) {
            int ee = (e + qd) & 3;
            sm[(qd * 4 + ee) * XS_STRIDE + ch] = bs[ee];
        }
    }
    __syncthreads();   // B0

    ushort* priv = &sm[XS_SIZE + wv * WPRIV];

    // ---------------- pass A: q,k projection (4 m-tiles x 4 p-tiles) ----------------
    f32x4 acc[4][4];
    #pragma unroll
    for (int i = 0; i < 4; ++i)
        #pragma unroll
        for (int j = 0; j < 4; ++j)
            acc[i][j] = (f32x4){0.f, 0.f, 0.f, 0.f};

    const ushort* wr[4];
    #pragma unroll
    for (int j = 0; j < 4; ++j) {
        int m0 = (j >> 1) * 256 + head * 32 + (j & 1) * 16;   // sect 0=q,1=k
        wr[j] = wqkvb + (size_t)(m0 + c) * 256;
    }

    #pragma unroll
    for (int ks = 0; ks < 8; ++ks) {
        bf16x8 bfr[4];
        #pragma unroll
        for (int pt = 0; pt < 4; ++pt)
            bfr[pt] = *(const bf16x8*)&sm[(pt * 16 + c) * XS_STRIDE + ks * 32 + 8 * g];
        #pragma unroll
        for (int j = 0; j < 4; ++j) {
            bf16x8 afr = *(const bf16x8*)(wr[j] + ks * 32 + 8 * g);
            #pragma unroll
            for (int pt = 0; pt < 4; ++pt)
                acc[j][pt] = __builtin_amdgcn_mfma_f32_16x16x32_bf16(afr, bfr[pt], acc[j][pt], 0, 0, 0);
        }
    }

    // q epilogue -> Qt[pos][32d] stride 40 (injective: row len 32 <= 40)
    #pragma unroll
    for (int mt = 0; mt < 2; ++mt) {
        f32x4 bq = *(const f32x4*)&bqkv[head * 32 + mt * 16 + 4 * g];
        #pragma unroll
        for (int pt = 0; pt < 4; ++pt) {
            const int pos = pt * 16 + c;
            const float* pb = posb + (size_t)(head * 32 + mt * 16 + 4 * g) * 64 + pos;
            float v0 = (acc[mt][pt][0] + bq[0] + pb[0])   * ATT_SCALE;
            float v1 = (acc[mt][pt][1] + bq[1] + pb[64])  * ATT_SCALE;
            float v2 = (acc[mt][pt][2] + bq[2] + pb[128]) * ATT_SCALE;
            float v3 = (acc[mt][pt][3] + bq[3] + pb[192]) * ATT_SCALE;
            *(unsigned*)&priv[pos * 40 + mt * 16 + 4 * g]     = pack2(v0, v1);
            *(unsigned*)&priv[pos * 40 + mt * 16 + 4 * g + 2] = pack2(v2, v3);
        }
    }
    bf16x8 qf[4];
    #pragma unroll
    for (int qt = 0; qt < 4; ++qt)
        qf[qt] = *(const bf16x8*)&priv[(qt * 16 + c) * 40 + 8 * g];

    // k epilogue -> Kt (same slots; same-wave RAW through in-order DS pipe)
    #pragma unroll
    for (int mt = 0; mt < 2; ++mt) {
        f32x4 bk = *(const f32x4*)&bqkv[256 + head * 32 + mt * 16 + 4 * g];
        #pragma unroll
        for (int pt = 0; pt < 4; ++pt) {
            const int pos = pt * 16 + c;
            *(unsigned*)&priv[pos * 40 + mt * 16 + 4 * g]     = pack2(acc[mt + 2][pt][0] + bk[0], acc[mt + 2][pt][1] + bk[1]);
            *(unsigned*)&priv[pos * 40 + mt * 16 + 4 * g + 2] = pack2(acc[mt + 2][pt][2] + bk[2], acc[mt + 2][pt][3] + bk[3]);
        }
    }
    bf16x8 kf[4];
    #pragma unroll
    for (int kt = 0; kt < 4; ++kt)
        kf[kt] = *(const bf16x8*)&priv[(kt * 16 + c) * 40 + 8 * g];

    // ---------------- pass B: v projection (2 m-tiles x 4 p-tiles) ----------------
    f32x4 av[2][4];
    #pragma unroll
    for (int i = 0; i < 2; ++i)
        #pragma unroll
        for (int j = 0; j < 4; ++j)
            av[i][j] = (f32x4){0.f, 0.f, 0.f, 0.f};
    const ushort* wv0 = wqkvb + (size_t)(512 + head * 32 + c) * 256;
    const ushort* wv1 = wqkvb + (size_t)(512 + head * 32 + 16 + c) * 256;

    #pragma unroll
    for (int ks = 0; ks < 8; ++ks) {
        bf16x8 bfr[4];
        #pragma unroll
        for (int pt = 0; pt < 4; ++pt)
            bfr[pt] = *(const bf16x8*)&sm[(pt * 16 + c) * XS_STRIDE + ks * 32 + 8 * g];
        bf16x8 a0 = *(const bf16x8*)(wv0 + ks * 32 + 8 * g);
        bf16x8 a1 = *(const bf16x8*)(wv1 + ks * 32 + 8 * g);
        #pragma unroll
        for (int pt = 0; pt < 4; ++pt) {
            av[0][pt] = __builtin_amdgcn_mfma_f32_16x16x32_bf16(a0, bfr[pt], av[0][pt], 0, 0, 0);
            av[1][pt] = __builtin_amdgcn_mfma_f32_16x16x32_bf16(a1, bfr[pt], av[1][pt], 0, 0, 0);
        }
    }

    // v epilogue -> VT[32 d][64 pos] STRIDE 72 (injective: 64 <= 72; 32*72=2304 <= 2560)
    // overwrites Qt/Kt rows; qf/kf already in regs.
    #pragma unroll
    for (int mt = 0; mt < 2; ++mt) {
        f32x4 bv = *(const f32x4*)&bqkv[512 + head * 32 + mt * 16 + 4 * g];
        #pragma unroll
        for (int pt = 0; pt < 4; ++pt) {
            #pragma unroll
            for (int r = 0; r < 4; ++r)
                priv[(mt * 16 + 4 * g + r) * 72 + pt * 16 + c] = f2bf(av[mt][pt][r] + bv[r]);
        }
    }

    // ---------------- attention (fully wave-private, no barriers) ----------------
    f32x4 s[4][4];   // [kt][qt]: D row = key kt*16+4g+r, col = query qt*16+c
    #pragma unroll
    for (int kt = 0; kt < 4; ++kt)
        #pragma unroll
        for (int qt = 0; qt < 4; ++qt)
            s[kt][qt] = __builtin_amdgcn_mfma_f32_16x16x32_bf16(kf[kt], qf[qt],
                                                                (f32x4){0.f,0.f,0.f,0.f}, 0, 0, 0);

    float rinv[4];
    #pragma unroll
    for (int qt = 0; qt < 4; ++qt) {
        float mx = s[0][qt][0];
        #pragma unroll
        for (int kt = 0; kt < 4; ++kt)
            #pragma unroll
            for (int r = 0; r < 4; ++r)
                mx = fmaxf(mx, s[kt][qt][r]);
        mx = fmaxf(mx, __shfl_xor(mx, 16));
        mx = fmaxf(mx, __shfl_xor(mx, 32));
        float sum = 0.f;
        #pragma unroll
        for (int kt = 0; kt < 4; ++kt)
            #pragma unroll
            for (int r = 0; r < 4; ++r) {
                s[kt][qt][r] = __expf(s[kt][qt][r] - mx);
                sum += s[kt][qt][r];
            }
        sum += __shfl_xor(sum, 16);
        sum += __shfl_xor(sum, 32);
        rinv[qt] = 1.0f / sum;
    }

    // vf BEFORE P overwrites VT
    bf16x8 vf[2][2];
    #pragma unroll
    for (int dt = 0; dt < 2; ++dt)
        #pragma unroll
        for (int k2 = 0; k2 < 2; ++k2)
            vf[dt][k2] = *(const bf16x8*)&priv[(dt * 16 + c) * 72 + k2 * 32 + 8 * g];

    // PV in two sequential key-half generations through the same P slots
    f32x4 o[2][4];
    #pragma unroll
    for (int dt = 0; dt < 2; ++dt)
        #pragma unroll
        for (int qt = 0; qt < 4; ++qt)
            o[dt][qt] = (f32x4){0.f,0.f,0.f,0.f};

    #pragma unroll
    for (int k2 = 0; k2 < 2; ++k2) {
        // write P[q][local key 0..31] stride 40 from s[2*k2], s[2*k2+1]
        #pragma unroll
        for (int qt = 0; qt < 4; ++qt)
            #pragma unroll
            for (int kl = 0; kl < 2; ++kl) {
                const int kt = k2 * 2 + kl;
                *(unsigned*)&priv[(qt * 16 + c) * 40 + kl * 16 + 4 * g]     = pack2(s[kt][qt][0], s[kt][qt][1]);
                *(unsigned*)&priv[(qt * 16 + c) * 40 + kl * 16 + 4 * g + 2] = pack2(s[kt][qt][2], s[kt][qt][3]);
            }
        #pragma unroll
        for (int qt = 0; qt < 4; ++qt) {
            bf16x8 pf = *(const bf16x8*)&priv[(qt * 16 + c) * 40 + 8 * g];
            #pragma unroll
            for (int dt = 0; dt < 2; ++dt)
                o[dt][qt] = __builtin_amdgcn_mfma_f32_16x16x32_bf16(vf[dt][k2], pf, o[dt][qt], 0, 0, 0);
        }
    }

    __syncthreads();   // B1: every wave done reading xs; o may overlay it

    // o -> os[pos][ch] (xs overlay)
    #pragma unroll
    for (int dt = 0; dt < 2; ++dt)
        #pragma unroll
        for (int qt = 0; qt < 4; ++qt) {
            const int pos = qt * 16 + c;
            const int ch0 = head * 32 + dt * 16 + 4 * g;
            float rv = rinv[qt];
            *(unsigned*)&sm[pos * XS_STRIDE + ch0]     = pack2(o[dt][qt][0]*rv, o[dt][qt][1]*rv);
            *(unsigned*)&sm[pos * XS_STRIDE + ch0 + 2] = pack2(o[dt][qt][2]*rv, o[dt][qt][3]*rv);
        }
    __syncthreads();   // B2: os complete

    // ---------------- out projection: wave owns out-ch wv*32..+31, K=256 ----------------
    f32x4 ya[2][4];
    #pragma unroll
    for (int i = 0; i < 2; ++i)
        #pragma unroll
        for (int j = 0; j < 4; ++j)
            ya[i][j] = (f32x4){0.f,0.f,0.f,0.f};

    const ushort* wo0 = woutb + (size_t)(wv * 32 + c) * 256;
    const ushort* wo1 = woutb + (size_t)(wv * 32 + 16 + c) * 256;

    #pragma unroll
    for (int ks = 0; ks < 8; ++ks) {
        bf16x8 ofr[4];
        #pragma unroll
        for (int pt = 0; pt < 4; ++pt)
            ofr[pt] = *(const bf16x8*)&sm[(pt * 16 + c) * XS_STRIDE + ks * 32 + 8 * g];
        bf16x8 a0 = *(const bf16x8*)(wo0 + ks * 32 + 8 * g);
        bf16x8 a1 = *(const bf16x8*)(wo1 + ks * 32 + 8 * g);
        #pragma unroll
        for (int pt = 0; pt < 4; ++pt) {
            ya[0][pt] = __builtin_amdgcn_mfma_f32_16x16x32_bf16(a0, ofr[pt], ya[0][pt], 0, 0, 0);
            ya[1][pt] = __builtin_amdgcn_mfma_f32_16x16x32_bf16(a1, ofr[pt], ya[1][pt], 0, 0, 0);
        }
    }
    __syncthreads();   // B3: os reads done; ys may overlay

    // ---------------- epilogue: per-wave LDS transpose -> float4 y stores ----------------
    float* ys = (float*)sm;           // [128 col][66] f32; rows wave-private
    #pragma unroll
    for (int mt = 0; mt < 2; ++mt) {
        f32x4 bo = *(const f32x4*)&bout[wv * 32 + mt * 16 + 4 * g];
        #pragma unroll
        for (int pt = 0; pt < 4; ++pt) {
            const int pos = pt * 16 + c;
            #pragma unroll
            for (int r = 0; r < 4; ++r)
                ys[(wv * 16 + 4 * g + r) * 66 + pos] = ya[mt][pt][r] + bo[r];
        }
        #pragma unroll
        for (int k = 0; k < 2; ++k) {
            const int col = wv * 16 + k * 8 + (lane >> 3);
            const int hh  = lane & 7;
            float2 p0 = *(float2*)&ys[col * 66 + hh * 8];
            float2 p1 = *(float2*)&ys[col * 66 + hh * 8 + 2];
            float2 p2 = *(float2*)&ys[col * 66 + hh * 8 + 4];
            float2 p3 = *(float2*)&ys[col * 66 + hh * 8 + 6];
            const int co  = ((col >> 4) * 2 + mt) * 16 + (col & 15);
            const int him = wi * 8 + hh - 4;
            if ((unsigned)him < 128u) {
                float* yrow = y + (((size_t)b * 256 + co) * 128 + him) * 128;
                if (wj > 0)  { f32x4 v0 = {p0.x, p0.y, p1.x, p1.y}; *(f32x4*)&yrow[wbase]     = v0; }
                if (wj < 16) { f32x4 v1 = {p2.x, p2.y, p3.x, p3.y}; *(f32x4*)&yrow[wbase + 4] = v1; }
            }
        }
    }
}

extern "C" void kernel_launch(void* const* d_in, const int* in_sizes, int n_in,
                              void* d_out, int out_size, void* d_ws, size_t ws_size,
                              hipStream_t stream)
{
    const float* x    = (const float*)d_in[0];
    const float* wqkv = (const float*)d_in[1];
    const float* bqkv = (const float*)d_in[2];
    const float* posb = (const float*)d_in[3];
    const float* wout = (const float*)d_in[4];
    const float* bout = (const float*)d_in[5];
    float* y = (float*)d_out;

    ushort* wqkvb = (ushort*)d_ws;            // 196608 bf16
    ushort* woutb = wqkvb + 196608;           // 65536 bf16

    lsa_wconv<<<dim3(1024), dim3(256), 0, stream>>>(wqkv, wout, wqkvb);
    lsa_fused<<<dim3(4 * NWIN), dim3(512), 0, stream>>>(x, bqkv, posb, bout, wqkvb, woutb, y);
}